// Round 6
// baseline (150.460 us; speedup 1.0000x reference)
//
#include <hip/hip_runtime.h>
#include <hip/hip_bf16.h>
#include <math.h>

// SupCon loss, N=8192 D=128 fp32 in, scalar fp32 out.
// Round 9: Falsification experiment -- sim has NO device atomics at all.
// History: 46us sim wall with all pipes <30% survived removal of per-tile
// atomics (R6), LDS+barriers+bank-conflicts (R7), and I$/code-size (R8).
// Last structural invariant: 524K device-scope fp32 atomicAdds at block end,
// 16 blocks x 2 waves RMW-ing the same 1024 lines cross-XCD (~200cyc/bounce
// x 512 ops/line ~ 43us serialization, invisible to SQ counters).
// Fix: block (ti,g), wave (wy,wx) plain-stores its 32 row-partials into a
// private slice part[E|P][gi*32 + g*2 + wx] (2MB staging, each slot written
// exactly once -- zero contention). finalize sums 32 partials/row (+2MB
// coalesced reads). prep zeroes nothing. Data path otherwise identical to R8
// (fragment-major Fb in L2, no LDS, no barriers, A-frags in regs, #unroll 1).

constexpr int N = 8192;
constexpr int D = 128;

typedef __attribute__((ext_vector_type(8))) short short8;  // 8 bf16 = 4 VGPRs
typedef __attribute__((ext_vector_type(4))) float f32x4;

constexpr float SELF_POISON = -50.0f;  // exp2(-50) ~ 9e-16; |s2| <= 14.43 real

__device__ __forceinline__ float fast_exp2(float x) {
#if __has_builtin(__builtin_amdgcn_exp2f)
    return __builtin_amdgcn_exp2f(x);
#else
    return __expf(x * 0.69314718056f);
#endif
}

// ---------------- prep: bf16 rows scaled into log2 domain, fragment layout --
// FbP uint index for element pair (row, k=2l): (row>>4)*1024 + (l>>2)*64 +
// (row&15)*4 + (l&3). Chunk chi = l>>2 holds k = 8*chi .. 8*chi+7 in order.
__global__ void prep_kernel(const float* __restrict__ F,
                            unsigned int* __restrict__ FbP) {
    int row = blockIdx.x * 4 + (threadIdx.x >> 6);
    int l = threadIdx.x & 63;
    float2 v = ((const float2*)(F + (size_t)row * D))[l];
    float ss = v.x * v.x + v.y * v.y;
#pragma unroll
    for (int off = 32; off > 0; off >>= 1) ss += __shfl_xor(ss, off);
    float sc = sqrtf(14.4269504089f / ss);  // 10 * log2(e), folded
    __hip_bfloat16 hx = __float2bfloat16(v.x * sc);
    __hip_bfloat16 hy = __float2bfloat16(v.y * sc);
    unsigned int ux = *(unsigned short*)&hx;
    unsigned int uy = *(unsigned short*)&hy;
    unsigned int idx = ((unsigned)(row >> 4) << 10) | ((unsigned)(l >> 2) << 6) |
                       ((unsigned)(row & 15) << 2) | (unsigned)(l & 3);
    FbP[idx] = ux | (uy << 16);
}

// ---------------- sim: full matrix, MFMA, no LDS, no barriers, NO ATOMICS ---
__global__ __launch_bounds__(256, 2) void sim_kernel(
    const short8* __restrict__ P, const int* __restrict__ labels,
    float* __restrict__ partE, float* __restrict__ partP) {
    const int ti = blockIdx.x >> 4;   // 64 row tiles
    const int g  = blockIdx.x & 15;   // 16 column groups
    const int tjs = g * 4;
    const int i0 = ti * 128;

    const int t = threadIdx.x, w = t >> 6, l = t & 63;
    const int c = l & 15, quad = l >> 4;    // MFMA lane split
    const int wy = w >> 1, wx = w & 1;      // 64x64 quadrant per wave

    // A fragments for the whole strip: 16 x 1KB coalesced loads, 64 VGPR.
    short8 Af[4][4];  // [kk][m]
#pragma unroll
    for (int kk = 0; kk < 4; ++kk)
#pragma unroll
        for (int m = 0; m < 4; ++m)
            Af[kk][m] = P[(ti * 8 + wy * 4 + m) * 256 + kk * 64 + l];

    // row labels for this wave's rows (strip-constant)
    int li[4][4];
#pragma unroll
    for (int m = 0; m < 4; ++m)
#pragma unroll
        for (int r = 0; r < 4; ++r)
            li[m][r] = labels[i0 + wy * 64 + m * 16 + quad * 4 + r];

    const bool selfQuad = (quad == (c >> 2));  // lane may hold self elements

    float RE[4][4] = {}, RP[4][4] = {};  // row partials, carried across strip

#pragma unroll 1
    for (int tj = tjs; tj < tjs + 4; ++tj) {
        const int j0 = tj * 128;
        int lj[4];
#pragma unroll
        for (int n = 0; n < 4; ++n) lj[n] = labels[j0 + wx * 64 + n * 16 + c];

        f32x4 acc[4][4] = {};
#pragma unroll
        for (int kk = 0; kk < 4; ++kk) {
            short8 bf[4];
#pragma unroll
            for (int n = 0; n < 4; ++n)
                bf[n] = P[(tj * 8 + wx * 4 + n) * 256 + kk * 64 + l];
#pragma unroll
            for (int m = 0; m < 4; ++m)
#pragma unroll
                for (int n = 0; n < 4; ++n)
                    acc[m][n] = __builtin_amdgcn_mfma_f32_16x16x32_bf16(
                        Af[kk][m], bf[n], acc[m][n], 0, 0, 0);
        }

        // Diagonal tile: poison self elements so the clean epilogue naturally
        // zeroes them (exp2(-50)~0; the -50 entering RP is corrected at store).
        if (tj == ti && wy == wx) {
#pragma unroll
            for (int m = 0; m < 4; ++m)
#pragma unroll
                for (int r = 0; r < 4; ++r) {
                    bool cond = selfQuad && (r == (c & 3));
                    acc[m][m][r] = cond ? SELF_POISON : acc[m][m][r];
                }
        }

        // ---- minimal row-only epilogue: 5 insts per element ----
#pragma unroll
        for (int m = 0; m < 4; ++m) {
#pragma unroll
            for (int n = 0; n < 4; ++n) {
#pragma unroll
                for (int r = 0; r < 4; ++r) {
                    float s2 = acc[m][n][r];
                    RE[m][r] += fast_exp2(s2);
                    RP[m][r] += (li[m][r] == lj[n]) ? s2 : 0.0f;
                }
            }
        }
    }

    // strip end: row reduction across the 16 col-lanes, then PLAIN STORES to
    // this block+wave's private slice. No atomics anywhere in this kernel.
#pragma unroll
    for (int m = 0; m < 4; ++m)
#pragma unroll
        for (int r = 0; r < 4; ++r) {
#pragma unroll
            for (int off = 1; off < 16; off <<= 1) {
                RE[m][r] += __shfl_xor(RE[m][r], off);
                RP[m][r] += __shfl_xor(RP[m][r], off);
            }
        }
    if (c == 0) {
        // undo the diag poison injected into the positive-sums: exactly one
        // -50 per (m,r) row group in waves wy==wx of diag-containing blocks.
        if (g == (ti >> 2) && wy == wx) {
#pragma unroll
            for (int m = 0; m < 4; ++m)
#pragma unroll
                for (int r = 0; r < 4; ++r) RP[m][r] -= SELF_POISON;
        }
        const int slot = g * 2 + wx;  // 32 private slots per row
#pragma unroll
        for (int m = 0; m < 4; ++m)
#pragma unroll
            for (int r = 0; r < 4; ++r) {
                int gi = i0 + wy * 64 + m * 16 + quad * 4 + r;
                partE[(size_t)gi * 32 + slot] = RE[m][r];
                partP[(size_t)gi * 32 + slot] = RP[m][r];
            }
    }
}

// ---------------- finalize: sum 32 partials/row, hist, loss -----------------
__global__ void finalize_kernel(const float* __restrict__ partE,
                                const float* __restrict__ partP,
                                const int* __restrict__ labels,
                                float* __restrict__ out) {
    __shared__ int hist[1024];
    __shared__ float ws16[16];
    int t = threadIdx.x;  // 1024 threads
    hist[t] = 0;
    __syncthreads();
    int lab[8];
#pragma unroll
    for (int k = 0; k < 8; ++k) {
        lab[k] = labels[t + 1024 * k];
        atomicAdd(&hist[lab[k]], 1);
    }
    __syncthreads();
    float a = 0.0f;
#pragma unroll
    for (int k = 0; k < 8; ++k) {
        int i = t + 1024 * k;
        float se = 0.0f, sp = 0.0f;
#pragma unroll
        for (int j = 0; j < 8; ++j) {
            f32x4 ve = ((const f32x4*)(partE + (size_t)i * 32))[j];
            f32x4 vp = ((const f32x4*)(partP + (size_t)i * 32))[j];
            se += ve[0] + ve[1] + ve[2] + ve[3];
            sp += vp[0] + vp[1] + vp[2] + vp[3];
        }
        int cnt = hist[lab[k]] - 1;
        if (cnt > 0)
            a += logf(se + 1e-9f) - 0.69314718056f * sp / (float)cnt;
    }
#pragma unroll
    for (int off = 32; off > 0; off >>= 1) a += __shfl_xor(a, off);
    if ((t & 63) == 0) ws16[t >> 6] = a;
    __syncthreads();
    if (t == 0) {
        float s = 0.0f;
#pragma unroll
        for (int i = 0; i < 16; ++i) s += ws16[i];
        out[0] = s / (float)N;
    }
}

extern "C" void kernel_launch(void* const* d_in, const int* in_sizes, int n_in,
                              void* d_out, int out_size, void* d_ws, size_t ws_size,
                              hipStream_t stream) {
    const float* F      = (const float*)d_in[0];
    const int*   labels = (const int*)d_in[1];
    float* out = (float*)d_out;

    unsigned int* FbP = (unsigned int*)d_ws;                 // 2 MB
    float* partE = (float*)((char*)d_ws + (size_t)2 * 1024 * 1024);  // 1 MB
    float* partP = partE + (size_t)N * 32;                   // 1 MB

    prep_kernel<<<N / 4, 256, 0, stream>>>(F, FbP);
    sim_kernel<<<64 * 16, 256, 0, stream>>>((const short8*)FbP, labels, partE,
                                            partP);
    finalize_kernel<<<1, 1024, 0, stream>>>(partE, partP, labels, out);
}

// Round 7
// 102.363 us; speedup vs baseline: 1.4699x; 1.4699x over previous
//
#include <hip/hip_runtime.h>
#include <hip/hip_bf16.h>
#include <math.h>

// SupCon loss, N=8192 D=128 fp32 in, scalar fp32 out.
// Round 10: R9 proved the device-atomic theory (sim 46 -> ~35us once atomics
// were replaced by private partial stores) but serialized the reduction into a
// single-block finalize reading 2MB on one CU (59.8us, the new top dispatch).
// Fix: parallel reduction. zero(hist,out) -> prep(+hist atomics, R0-known-good)
// -> sim (R9, untouched: no LDS/barriers/atomics, fragment-major L2 streams)
// -> reduce: 128 blocks; one row per 32-lane half-wave (coalesced lane-load +
// 5-level shfl butterfly), per-row loss term, block reduce, one scaled
// atomicAdd to out per block (128 total).

constexpr int N = 8192;
constexpr int D = 128;

typedef __attribute__((ext_vector_type(8))) short short8;  // 8 bf16 = 4 VGPRs
typedef __attribute__((ext_vector_type(4))) float f32x4;

constexpr float SELF_POISON = -50.0f;  // exp2(-50) ~ 9e-16; |s2| <= 14.43 real

__device__ __forceinline__ float fast_exp2(float x) {
#if __has_builtin(__builtin_amdgcn_exp2f)
    return __builtin_amdgcn_exp2f(x);
#else
    return __expf(x * 0.69314718056f);
#endif
}

// ---------------- zero: hist + output accumulator ---------------------------
__global__ void zero_kernel(int* __restrict__ hist, float* __restrict__ out) {
    hist[threadIdx.x] = 0;  // <<<1,1024>>>
    if (threadIdx.x == 0) out[0] = 0.0f;
}

// ---------------- prep: bf16 rows scaled into log2 domain, fragment layout --
// FbP uint index for element pair (row, k=2l): (row>>4)*1024 + (l>>2)*64 +
// (row&15)*4 + (l&3). Chunk chi = l>>2 holds k = 8*chi .. 8*chi+7 in order.
__global__ void prep_kernel(const float* __restrict__ F,
                            const int* __restrict__ labels,
                            unsigned int* __restrict__ FbP,
                            int* __restrict__ hist) {
    int row = blockIdx.x * 4 + (threadIdx.x >> 6);
    int l = threadIdx.x & 63;
    float2 v = ((const float2*)(F + (size_t)row * D))[l];
    float ss = v.x * v.x + v.y * v.y;
#pragma unroll
    for (int off = 32; off > 0; off >>= 1) ss += __shfl_xor(ss, off);
    float sc = sqrtf(14.4269504089f / ss);  // 10 * log2(e), folded
    __hip_bfloat16 hx = __float2bfloat16(v.x * sc);
    __hip_bfloat16 hy = __float2bfloat16(v.y * sc);
    unsigned int ux = *(unsigned short*)&hx;
    unsigned int uy = *(unsigned short*)&hy;
    unsigned int idx = ((unsigned)(row >> 4) << 10) | ((unsigned)(l >> 2) << 6) |
                       ((unsigned)(row & 15) << 2) | (unsigned)(l & 3);
    FbP[idx] = ux | (uy << 16);
    if (l == 0) atomicAdd(&hist[labels[row]], 1);
}

// ---------------- sim: full matrix, MFMA, no LDS, no barriers, NO ATOMICS ---
__global__ __launch_bounds__(256, 2) void sim_kernel(
    const short8* __restrict__ P, const int* __restrict__ labels,
    float* __restrict__ partE, float* __restrict__ partP) {
    const int ti = blockIdx.x >> 4;   // 64 row tiles
    const int g  = blockIdx.x & 15;   // 16 column groups
    const int tjs = g * 4;
    const int i0 = ti * 128;

    const int t = threadIdx.x, w = t >> 6, l = t & 63;
    const int c = l & 15, quad = l >> 4;    // MFMA lane split
    const int wy = w >> 1, wx = w & 1;      // 64x64 quadrant per wave

    // A fragments for the whole strip: 16 x 1KB coalesced loads, 64 VGPR.
    short8 Af[4][4];  // [kk][m]
#pragma unroll
    for (int kk = 0; kk < 4; ++kk)
#pragma unroll
        for (int m = 0; m < 4; ++m)
            Af[kk][m] = P[(ti * 8 + wy * 4 + m) * 256 + kk * 64 + l];

    // row labels for this wave's rows (strip-constant)
    int li[4][4];
#pragma unroll
    for (int m = 0; m < 4; ++m)
#pragma unroll
        for (int r = 0; r < 4; ++r)
            li[m][r] = labels[i0 + wy * 64 + m * 16 + quad * 4 + r];

    const bool selfQuad = (quad == (c >> 2));  // lane may hold self elements

    float RE[4][4] = {}, RP[4][4] = {};  // row partials, carried across strip

#pragma unroll 1
    for (int tj = tjs; tj < tjs + 4; ++tj) {
        const int j0 = tj * 128;
        int lj[4];
#pragma unroll
        for (int n = 0; n < 4; ++n) lj[n] = labels[j0 + wx * 64 + n * 16 + c];

        f32x4 acc[4][4] = {};
#pragma unroll
        for (int kk = 0; kk < 4; ++kk) {
            short8 bf[4];
#pragma unroll
            for (int n = 0; n < 4; ++n)
                bf[n] = P[(tj * 8 + wx * 4 + n) * 256 + kk * 64 + l];
#pragma unroll
            for (int m = 0; m < 4; ++m)
#pragma unroll
                for (int n = 0; n < 4; ++n)
                    acc[m][n] = __builtin_amdgcn_mfma_f32_16x16x32_bf16(
                        Af[kk][m], bf[n], acc[m][n], 0, 0, 0);
        }

        // Diagonal tile: poison self elements so the clean epilogue naturally
        // zeroes them (exp2(-50)~0; the -50 entering RP is corrected at store).
        if (tj == ti && wy == wx) {
#pragma unroll
            for (int m = 0; m < 4; ++m)
#pragma unroll
                for (int r = 0; r < 4; ++r) {
                    bool cond = selfQuad && (r == (c & 3));
                    acc[m][m][r] = cond ? SELF_POISON : acc[m][m][r];
                }
        }

        // ---- minimal row-only epilogue: 5 insts per element ----
#pragma unroll
        for (int m = 0; m < 4; ++m) {
#pragma unroll
            for (int n = 0; n < 4; ++n) {
#pragma unroll
                for (int r = 0; r < 4; ++r) {
                    float s2 = acc[m][n][r];
                    RE[m][r] += fast_exp2(s2);
                    RP[m][r] += (li[m][r] == lj[n]) ? s2 : 0.0f;
                }
            }
        }
    }

    // strip end: row reduction across the 16 col-lanes, then PLAIN STORES to
    // this block+wave's private slice. No atomics anywhere in this kernel.
#pragma unroll
    for (int m = 0; m < 4; ++m)
#pragma unroll
        for (int r = 0; r < 4; ++r) {
#pragma unroll
            for (int off = 1; off < 16; off <<= 1) {
                RE[m][r] += __shfl_xor(RE[m][r], off);
                RP[m][r] += __shfl_xor(RP[m][r], off);
            }
        }
    if (c == 0) {
        // undo the diag poison injected into the positive-sums: exactly one
        // -50 per (m,r) row group in waves wy==wx of diag-containing blocks.
        if (g == (ti >> 2) && wy == wx) {
#pragma unroll
            for (int m = 0; m < 4; ++m)
#pragma unroll
                for (int r = 0; r < 4; ++r) RP[m][r] -= SELF_POISON;
        }
        const int slot = g * 2 + wx;  // 32 private slots per row
#pragma unroll
        for (int m = 0; m < 4; ++m)
#pragma unroll
            for (int r = 0; r < 4; ++r) {
                int gi = i0 + wy * 64 + m * 16 + quad * 4 + r;
                partE[(size_t)gi * 32 + slot] = RE[m][r];
                partP[(size_t)gi * 32 + slot] = RP[m][r];
            }
    }
}

// ---------------- reduce: 128 blocks; one row per 32-lane half-wave ---------
// Sums the 32 partials per row, computes the per-row loss term, block-reduces,
// one scaled atomicAdd per block into out[0].
__global__ void reduce_kernel(const float* __restrict__ partE,
                              const float* __restrict__ partP,
                              const int* __restrict__ labels,
                              const int* __restrict__ hist,
                              float* __restrict__ out) {
    __shared__ float ws4[4];
    const int t = threadIdx.x, w = t >> 6, l = t & 63;
    const int half = l >> 5, sl = l & 31;
    const int rbase = blockIdx.x * 64 + w * 16;  // 64 rows/block, 16/wave

    float a = 0.0f;
#pragma unroll
    for (int it = 0; it < 8; ++it) {
        int row = rbase + it * 2 + half;
        float se = partE[(size_t)row * 32 + sl];
        float sp = partP[(size_t)row * 32 + sl];
#pragma unroll
        for (int off = 1; off < 32; off <<= 1) {
            se += __shfl_xor(se, off);
            sp += __shfl_xor(sp, off);
        }
        if (sl == 0) {
            int cnt = hist[labels[row]] - 1;
            if (cnt > 0)
                a += logf(se + 1e-9f) - 0.69314718056f * sp / (float)cnt;
        }
    }
    // wave reduce (only lanes sl==0 carry nonzero a)
#pragma unroll
    for (int off = 1; off < 64; off <<= 1) a += __shfl_xor(a, off);
    if (l == 0) ws4[w] = a;
    __syncthreads();
    if (t == 0) {
        float s = ws4[0] + ws4[1] + ws4[2] + ws4[3];
        atomicAdd(out, s * (1.0f / (float)N));
    }
}

extern "C" void kernel_launch(void* const* d_in, const int* in_sizes, int n_in,
                              void* d_out, int out_size, void* d_ws, size_t ws_size,
                              hipStream_t stream) {
    const float* F      = (const float*)d_in[0];
    const int*   labels = (const int*)d_in[1];
    float* out = (float*)d_out;

    unsigned int* FbP = (unsigned int*)d_ws;                         // 2 MB
    float* partE = (float*)((char*)d_ws + (size_t)2 * 1024 * 1024);  // 1 MB
    float* partP = partE + (size_t)N * 32;                           // 1 MB
    int*   hist  = (int*)(partP + (size_t)N * 32);                   // 4 KB

    zero_kernel<<<1, 1024, 0, stream>>>(hist, out);
    prep_kernel<<<N / 4, 256, 0, stream>>>(F, labels, FbP, hist);
    sim_kernel<<<64 * 16, 256, 0, stream>>>((const short8*)FbP, labels, partE,
                                            partP);
    reduce_kernel<<<128, 256, 0, stream>>>(partE, partP, labels, hist, out);
}